// Round 13
// baseline (159.091 us; speedup 1.0000x reference)
//
#include <hip/hip_runtime.h>

// GMLoss: bidirectional chamfer min + Geman-McClure penalty (MU=1).
// srcs, tgts: [B=8, D=3, N=4096] fp32. Output: scalar fp32.
//
// R13 = R12 (77.2us) with 128 query rows per block (was 32). Theory: R12's
// chamfer was L1-delivery-bound, not VALU-bound: 2048 blocks x 128KB Bpack
// = 268MB unique / 537MB delivered (quad duplication) ~= 14us of texture
// pipe. B-traffic per block is FIXED (128KB), so 4x rows/block divides it
// by 4: 512 blocks -> 67MB unique / 134MB delivered ~= 3.4us < VALU term.
// Per B-load now 8 MFMAs (8 row-tiles). VGPR: 8 A-frags(32) + 8 rmin
// floatx4(32) + ring(32) + misc ~= 115 < 128 cap -> stays in VGPRs (R12
// lesson: floatx16 accs got exiled to AGPRs).
// Grid 512x512thr = exactly 2 blocks/CU, 4 waves/SIMD.
//
// Kept from R8-R12 (all verified absmax 0.0): plain stores + tiny finish
// kernel (NO fences/hot atomics - R7/R9 lessons), XCD swizzle group=blk&15,
// depth-4 register prefetch ring, 16x16x32 MFMA with K-replication (D=2P,
// halve after min), K=13 hi/lo-split packing:
//   A k: [-2sh(3), -2sl(3), -2sh(3), s2h, s2l, 1, 1, 0,0,0]
//   B k: [ th(3),   th(3),   tl(3),  1, 1, t2h, t2l, 0,0,0]
//   dot = |s|^2+|t|^2-2s.t (drops sl.tl ~1e-5 << 1.26e-3 threshold).
// 16x16x32 layouts (m89/m91): A[m=lane&15][k=(lane>>4)*8+j], B same
// (n=lane&15); D: col=lane&15, row=(lane>>4)*4+reg.

#define NPTS 4096
#define NB   8

typedef __attribute__((ext_vector_type(8))) short bf16x8;
typedef __attribute__((ext_vector_type(4))) float floatx4;

// ws layout: Apack[srcs], Apack[tgts], Bpack[srcs], Bpack[tgts], bsum[512]
#define OFF_APACK_S 0u
#define OFF_APACK_T (1u << 20)
#define OFF_BPACK_S (2u << 20)
#define OFF_BPACK_T (3u << 20)
#define OFF_BSUM    (4u << 20)

union V16 { int4 i; bf16x8 h; };

__device__ __forceinline__ unsigned short f2bf(float f) {
    unsigned u = __float_as_uint(f);
    u += 0x7FFFu + ((u >> 16) & 1u);       // RNE
    return (unsigned short)(u >> 16);
}
__device__ __forceinline__ float bf2f(unsigned short h) {
    return __uint_as_float(((unsigned)h) << 16);
}
__device__ __forceinline__ int pk(unsigned short lo, unsigned short hi) {
    return (int)((unsigned)lo | ((unsigned)hi << 16));
}

// ---------------- Kernel 1: pack A-style + B-style for both clouds --------
__device__ __forceinline__ void pack_point(const float* __restrict__ cloud,
                                           int b, int j, int gid,
                                           char* __restrict__ apack,
                                           char* __restrict__ bpack) {
    const unsigned short ONE = 0x3F80;
    const float* p = cloud + b * 3 * NPTS;
    const float x = p[j], y = p[NPTS + j], z = p[2 * NPTS + j];
    const unsigned short hx = f2bf(x), hy = f2bf(y), hz = f2bf(z);
    const unsigned short lx = f2bf(x - bf2f(hx));
    const unsigned short ly = f2bf(y - bf2f(hy));
    const unsigned short lz = f2bf(z - bf2f(hz));
    const unsigned short a0 = f2bf(-2.0f * bf2f(hx));
    const unsigned short a1 = f2bf(-2.0f * bf2f(hy));
    const unsigned short a2 = f2bf(-2.0f * bf2f(hz));
    const unsigned short m0 = f2bf(-2.0f * (x - bf2f(hx)));
    const unsigned short m1 = f2bf(-2.0f * (y - bf2f(hy)));
    const unsigned short m2 = f2bf(-2.0f * (z - bf2f(hz)));
    const float n2 = fmaf(z, z, fmaf(y, y, x * x));
    const unsigned short n2h = f2bf(n2);
    const unsigned short n2l = f2bf(n2 - bf2f(n2h));

    int4* Ap = (int4*)(apack + (size_t)gid * 32);
    Ap[0] = make_int4(pk(a0, a1), pk(a2, m0), pk(m1, m2), pk(a0, a1));
    Ap[1] = make_int4(pk(a2, n2h), pk(n2l, ONE), pk(ONE, 0), 0);

    int4* Bp = (int4*)(bpack + (size_t)gid * 32);
    Bp[0] = make_int4(pk(hx, hy), pk(hz, hx), pk(hy, hz), pk(lx, ly));
    Bp[1] = make_int4(pk(lz, ONE), pk(ONE, n2h), pk(n2l, 0), 0);
}

__global__ __launch_bounds__(256)
void transform_kernel(const float* __restrict__ srcs,
                      const float* __restrict__ tgts,
                      char* __restrict__ ws) {
    const int gid = blockIdx.x * 256 + threadIdx.x;   // b*4096 + j
    const int b = gid >> 12, j = gid & 4095;
    pack_point(srcs, b, j, gid, ws + OFF_APACK_S, ws + OFF_BPACK_S);
    pack_point(tgts, b, j, gid, ws + OFF_APACK_T, ws + OFF_BPACK_T);
}

// ---------------- Kernel 2: row-min MFMA chamfer (16x16x32, 128 rows) -----
__global__ __launch_bounds__(512, 4)
void chamfer_kernel(char* __restrict__ ws) {
    const int blk    = blockIdx.x;        // 0..511
    const int group  = blk & 15;          // XCD-aware swizzle
    const int dir    = group >> 3;
    const int b      = group & 7;
    const int stripe = blk >> 4;          // 0..31, 128 query rows each
    const int tid    = threadIdx.x;
    const int wave   = tid >> 6;          // 0..7
    const int lane   = tid & 63;
    const int l15    = lane & 15;
    const int quad   = lane >> 4;         // k-half = (quad&1)*16 bytes

    const char* Ap = ws + (dir == 0 ? OFF_APACK_S : OFF_APACK_T);
    const char* Bp = ws + (dir == 0 ? OFF_BPACK_T : OFF_BPACK_S);

    // 8 row-tiles of 16 rows; quads 2,3 replicate quads 0,1 -> D = 2P.
    V16 av[8];
#pragma unroll
    for (int rt = 0; rt < 8; rt++)
        av[rt].i = *(const int4*)(Ap +
            (size_t)(b * NPTS + stripe * 128 + rt * 16 + l15) * 32 + (quad & 1) * 16);

    floatx4 rmin[8];
#pragma unroll
    for (int rt = 0; rt < 8; rt++)
        rmin[rt] = (floatx4){3.0e38f, 3.0e38f, 3.0e38f, 3.0e38f};
    const floatx4 zero = {0.0f, 0.0f, 0.0f, 0.0f};

    const int ct0 = wave * 32;            // 32 col-tiles (of 16 pts) per wave
    const char* bbase = Bp + (size_t)(b * NPTS + ct0 * 16 + l15) * 32 + (quad & 1) * 16;

    // depth-4 register prefetch ring over 32 tiles, 512 B apart; wrap &31
    V16 t0, t1, t2, t3;
    t0.i = *(const int4*)(bbase);
    t1.i = *(const int4*)(bbase + 512);
    t2.i = *(const int4*)(bbase + 1024);
    t3.i = *(const int4*)(bbase + 1536);

#pragma unroll
    for (int i = 0; i < 32; i += 4) {
        V16 n0, n1, n2, n3;
        n0.i = *(const int4*)(bbase + (size_t)((i + 4) & 31) * 512);
        n1.i = *(const int4*)(bbase + (size_t)((i + 5) & 31) * 512);
        n2.i = *(const int4*)(bbase + (size_t)((i + 6) & 31) * 512);
        n3.i = *(const int4*)(bbase + (size_t)((i + 7) & 31) * 512);
#pragma unroll
        for (int u = 0; u < 4; u++) {
            const bf16x8 bf = (u == 0 ? t0.h : u == 1 ? t1.h : u == 2 ? t2.h : t3.h);
#pragma unroll
            for (int rt = 0; rt < 8; rt++) {
                const floatx4 d =
                    __builtin_amdgcn_mfma_f32_16x16x32_bf16(av[rt].h, bf, zero, 0, 0, 0);
#pragma unroll
                for (int r = 0; r < 4; r++)
                    rmin[rt][r] = fminf(rmin[rt][r], d[r]);
            }
        }
        t0 = n0; t1 = n1; t2 = n2; t3 = n3;
    }

    // ---- butterfly min over the 16 col-lanes ----
#pragma unroll
    for (int off = 1; off < 16; off <<= 1) {
#pragma unroll
        for (int rt = 0; rt < 8; rt++)
#pragma unroll
            for (int r = 0; r < 4; r++)
                rmin[rt][r] = fminf(rmin[rt][r], __shfl_xor(rmin[rt][r], off, 64));
    }
    // quad leader holds rows rt*16 + quad*4 + r
    __shared__ float sRow[8][128];
    __shared__ float sRed[2];
    if (l15 == 0) {
#pragma unroll
        for (int rt = 0; rt < 8; rt++)
#pragma unroll
            for (int r = 0; r < 4; r++)
                sRow[wave][rt * 16 + quad * 4 + r] = rmin[rt][r];
    }
    __syncthreads();
    if (tid < 128) {
        float m = 3.0e38f;
#pragma unroll
        for (int w = 0; w < 8; w++) m = fminf(m, sRow[w][tid]);
        m = fmaxf(m * 0.5f, 0.0f);        // undo K-replication doubling
        float g = m / (m + 1.0f);         // GM, MU=1
#pragma unroll
        for (int off = 1; off < 64; off <<= 1)
            g += __shfl_xor(g, off, 64);
        if ((tid & 63) == 0) sRed[tid >> 6] = g;
    }
    __syncthreads();
    if (tid == 0)
        ((float*)(ws + OFF_BSUM))[blk] = sRed[0] + sRed[1];   // plain store
}

// ---------------- Kernel 3: single-block finish ----------------
__global__ __launch_bounds__(256)
void finish_kernel(const char* __restrict__ ws, float* __restrict__ out) {
    const float* bsum = (const float*)(ws + OFF_BSUM);
    const int tid = threadIdx.x;
    float g = bsum[tid] + bsum[tid + 256];                    // 512 entries
#pragma unroll
    for (int off = 1; off < 64; off <<= 1)
        g += __shfl_xor(g, off, 64);
    __shared__ float sp[4];
    if ((tid & 63) == 0) sp[tid >> 6] = g;
    __syncthreads();
    if (tid == 0)
        out[0] = (sp[0] + sp[1] + sp[2] + sp[3]) * (1.0f / (NB * NPTS));
}

extern "C" void kernel_launch(void* const* d_in, const int* in_sizes, int n_in,
                              void* d_out, int out_size, void* d_ws, size_t ws_size,
                              hipStream_t stream) {
    const float* srcs = (const float*)d_in[0];
    const float* tgts = (const float*)d_in[1];
    float* out = (float*)d_out;
    char* ws = (char*)d_ws;

    transform_kernel<<<dim3(128), dim3(256), 0, stream>>>(srcs, tgts, ws);
    chamfer_kernel<<<dim3(512), dim3(512), 0, stream>>>(ws);
    finish_kernel<<<dim3(1), dim3(256), 0, stream>>>(ws, out);
}

// Round 14
// 74.258 us; speedup vs baseline: 2.1424x; 2.1424x over previous
//
#include <hip/hip_runtime.h>

// GMLoss: bidirectional chamfer min + Geman-McClure penalty (MU=1).
// srcs, tgts: [B=8, D=3, N=4096] fp32. Output: scalar fp32.
//
// R14: fix the register-allocator squeeze R13 exposed. R13's chamfer:
// VGPR_Count=64, FETCH 120MB / WRITE 244MB = SCRATCH SPILL traffic -- at
// __launch_bounds__ cap 128 the compiler reserved ~64 regs for AGPR accs
// and spilled the rest of the ~115 live set to memory. Fix: 256-thread
// blocks with __launch_bounds__(256, 2) -> 256-reg cap; 64 rows/block
// (4 row-tiles), 4 waves x 64 col-tiles; live set ~80 regs -> no spill
// even with AGPR-resident accumulators.
//   - 1024 blocks = 4/CU, 4 waves/SIMD; L2 B-traffic 134MB (~4us).
//   - transform: one pack per thread (256 blocks, 2x parallelism of R13).
// Validation signal: chamfer VGPR_Count >= 90 AND WRITE_SIZE ~KB.
//
// Kept from R12 (77.2us best, absmax 0.0): 16x16x32 MFMA + K-replication
// (quads 2,3 reread bytes 0..31 -> D = 2P; halve after min), plain stores
// + tiny finish kernel (NO fences / NO hot atomics -- R7/R9 lessons), XCD
// swizzle group=blk&15, depth-4 register prefetch ring, K=13 hi/lo pack:
//   A k: [-2sh(3), -2sl(3), -2sh(3), s2h, s2l, 1, 1, 0,0,0]
//   B k: [ th(3),   th(3),   tl(3),  1, 1, t2h, t2l, 0,0,0]
//   dot = |s|^2+|t|^2-2s.t  (drops sl.tl ~1e-5 << 1.26e-3 threshold).
// 16x16x32 layouts (m89/m91): A[m=lane&15][k=(lane>>4)*8+j], B same
// (n=lane&15); D: col=lane&15, row=(lane>>4)*4+reg.

#define NPTS 4096
#define NB   8

typedef __attribute__((ext_vector_type(8))) short bf16x8;
typedef __attribute__((ext_vector_type(4))) float floatx4;

// ws layout: Apack[srcs], Apack[tgts], Bpack[srcs], Bpack[tgts], bsum[1024]
#define OFF_APACK_S 0u
#define OFF_APACK_T (1u << 20)
#define OFF_BPACK_S (2u << 20)
#define OFF_BPACK_T (3u << 20)
#define OFF_BSUM    (4u << 20)

union V16 { int4 i; bf16x8 h; };

__device__ __forceinline__ unsigned short f2bf(float f) {
    unsigned u = __float_as_uint(f);
    u += 0x7FFFu + ((u >> 16) & 1u);       // RNE
    return (unsigned short)(u >> 16);
}
__device__ __forceinline__ float bf2f(unsigned short h) {
    return __uint_as_float(((unsigned)h) << 16);
}
__device__ __forceinline__ int pk(unsigned short lo, unsigned short hi) {
    return (int)((unsigned)lo | ((unsigned)hi << 16));
}

// ---------------- Kernel 1: pack A-style + B-style, 1 point/thread --------
__device__ __forceinline__ void pack_point(const float* __restrict__ cloud,
                                           int b, int j, int gid,
                                           char* __restrict__ apack,
                                           char* __restrict__ bpack) {
    const unsigned short ONE = 0x3F80;
    const float* p = cloud + b * 3 * NPTS;
    const float x = p[j], y = p[NPTS + j], z = p[2 * NPTS + j];
    const unsigned short hx = f2bf(x), hy = f2bf(y), hz = f2bf(z);
    const unsigned short lx = f2bf(x - bf2f(hx));
    const unsigned short ly = f2bf(y - bf2f(hy));
    const unsigned short lz = f2bf(z - bf2f(hz));
    const unsigned short a0 = f2bf(-2.0f * bf2f(hx));
    const unsigned short a1 = f2bf(-2.0f * bf2f(hy));
    const unsigned short a2 = f2bf(-2.0f * bf2f(hz));
    const unsigned short m0 = f2bf(-2.0f * (x - bf2f(hx)));
    const unsigned short m1 = f2bf(-2.0f * (y - bf2f(hy)));
    const unsigned short m2 = f2bf(-2.0f * (z - bf2f(hz)));
    const float n2 = fmaf(z, z, fmaf(y, y, x * x));
    const unsigned short n2h = f2bf(n2);
    const unsigned short n2l = f2bf(n2 - bf2f(n2h));

    int4* Ap = (int4*)(apack + (size_t)gid * 32);
    Ap[0] = make_int4(pk(a0, a1), pk(a2, m0), pk(m1, m2), pk(a0, a1));
    Ap[1] = make_int4(pk(a2, n2h), pk(n2l, ONE), pk(ONE, 0), 0);

    int4* Bp = (int4*)(bpack + (size_t)gid * 32);
    Bp[0] = make_int4(pk(hx, hy), pk(hz, hx), pk(hy, hz), pk(lx, ly));
    Bp[1] = make_int4(pk(lz, ONE), pk(ONE, n2h), pk(n2l, 0), 0);
}

__global__ __launch_bounds__(256)
void transform_kernel(const float* __restrict__ srcs,
                      const float* __restrict__ tgts,
                      char* __restrict__ ws) {
    const int gid = blockIdx.x * 256 + threadIdx.x;   // 0..65535
    const int dir = gid >> 15;
    const int rem = gid & 32767;                      // b*4096 + j
    const int b = rem >> 12, j = rem & 4095;
    if (dir == 0)
        pack_point(srcs, b, j, rem, ws + OFF_APACK_S, ws + OFF_BPACK_S);
    else
        pack_point(tgts, b, j, rem, ws + OFF_APACK_T, ws + OFF_BPACK_T);
}

// ---------------- Kernel 2: row-min MFMA chamfer (16x16x32, 64 rows) ------
__global__ __launch_bounds__(256, 2)
void chamfer_kernel(char* __restrict__ ws) {
    const int blk    = blockIdx.x;        // 0..1023
    const int group  = blk & 15;          // XCD-aware swizzle
    const int dir    = group >> 3;
    const int b      = group & 7;
    const int stripe = blk >> 4;          // 0..63, 64 query rows each
    const int tid    = threadIdx.x;
    const int wave   = tid >> 6;          // 0..3
    const int lane   = tid & 63;
    const int l15    = lane & 15;
    const int quad   = lane >> 4;         // k-half = (quad&1)*16 bytes

    const char* Ap = ws + (dir == 0 ? OFF_APACK_S : OFF_APACK_T);
    const char* Bp = ws + (dir == 0 ? OFF_BPACK_T : OFF_BPACK_S);

    // 4 row-tiles of 16 rows; quads 2,3 replicate quads 0,1 -> D = 2P.
    V16 av[4];
#pragma unroll
    for (int rt = 0; rt < 4; rt++)
        av[rt].i = *(const int4*)(Ap +
            (size_t)(b * NPTS + stripe * 64 + rt * 16 + l15) * 32 + (quad & 1) * 16);

    floatx4 rmin[4];
#pragma unroll
    for (int rt = 0; rt < 4; rt++)
        rmin[rt] = (floatx4){3.0e38f, 3.0e38f, 3.0e38f, 3.0e38f};
    const floatx4 zero = {0.0f, 0.0f, 0.0f, 0.0f};

    const int ct0 = wave * 64;            // 64 col-tiles (of 16 pts) per wave
    const char* bbase = Bp + (size_t)(b * NPTS + ct0 * 16 + l15) * 32 + (quad & 1) * 16;

    // depth-4 register prefetch ring over 64 tiles, 512 B apart; wrap &63
    V16 t0, t1, t2, t3;
    t0.i = *(const int4*)(bbase);
    t1.i = *(const int4*)(bbase + 512);
    t2.i = *(const int4*)(bbase + 1024);
    t3.i = *(const int4*)(bbase + 1536);

#pragma unroll
    for (int i = 0; i < 64; i += 4) {
        V16 n0, n1, n2, n3;
        n0.i = *(const int4*)(bbase + (size_t)((i + 4) & 63) * 512);
        n1.i = *(const int4*)(bbase + (size_t)((i + 5) & 63) * 512);
        n2.i = *(const int4*)(bbase + (size_t)((i + 6) & 63) * 512);
        n3.i = *(const int4*)(bbase + (size_t)((i + 7) & 63) * 512);
#pragma unroll
        for (int u = 0; u < 4; u++) {
            const bf16x8 bf = (u == 0 ? t0.h : u == 1 ? t1.h : u == 2 ? t2.h : t3.h);
#pragma unroll
            for (int rt = 0; rt < 4; rt++) {
                const floatx4 d =
                    __builtin_amdgcn_mfma_f32_16x16x32_bf16(av[rt].h, bf, zero, 0, 0, 0);
#pragma unroll
                for (int r = 0; r < 4; r++)
                    rmin[rt][r] = fminf(rmin[rt][r], d[r]);
            }
        }
        t0 = n0; t1 = n1; t2 = n2; t3 = n3;
    }

    // ---- butterfly min over the 16 col-lanes ----
#pragma unroll
    for (int off = 1; off < 16; off <<= 1) {
#pragma unroll
        for (int rt = 0; rt < 4; rt++)
#pragma unroll
            for (int r = 0; r < 4; r++)
                rmin[rt][r] = fminf(rmin[rt][r], __shfl_xor(rmin[rt][r], off, 64));
    }
    // quad leader holds rows rt*16 + quad*4 + r
    __shared__ float sRow[4][64];
    if (l15 == 0) {
#pragma unroll
        for (int rt = 0; rt < 4; rt++)
#pragma unroll
            for (int r = 0; r < 4; r++)
                sRow[wave][rt * 16 + quad * 4 + r] = rmin[rt][r];
    }
    __syncthreads();
    if (tid < 64) {
        float m = fminf(fminf(sRow[0][tid], sRow[1][tid]),
                        fminf(sRow[2][tid], sRow[3][tid]));
        m = fmaxf(m * 0.5f, 0.0f);        // undo K-replication doubling
        float g = m / (m + 1.0f);         // GM, MU=1
#pragma unroll
        for (int off = 1; off < 64; off <<= 1)
            g += __shfl_xor(g, off, 64);
        if (tid == 0)
            ((float*)(ws + OFF_BSUM))[blk] = g;   // plain store
    }
}

// ---------------- Kernel 3: single-block finish ----------------
__global__ __launch_bounds__(256)
void finish_kernel(const char* __restrict__ ws, float* __restrict__ out) {
    const float* bsum = (const float*)(ws + OFF_BSUM);
    const int tid = threadIdx.x;
    float g = bsum[tid] + bsum[tid + 256] + bsum[tid + 512] + bsum[tid + 768];
#pragma unroll
    for (int off = 1; off < 64; off <<= 1)
        g += __shfl_xor(g, off, 64);
    __shared__ float sp[4];
    if ((tid & 63) == 0) sp[tid >> 6] = g;
    __syncthreads();
    if (tid == 0)
        out[0] = (sp[0] + sp[1] + sp[2] + sp[3]) * (1.0f / (NB * NPTS));
}

extern "C" void kernel_launch(void* const* d_in, const int* in_sizes, int n_in,
                              void* d_out, int out_size, void* d_ws, size_t ws_size,
                              hipStream_t stream) {
    const float* srcs = (const float*)d_in[0];
    const float* tgts = (const float*)d_in[1];
    float* out = (float*)d_out;
    char* ws = (char*)d_ws;

    transform_kernel<<<dim3(256), dim3(256), 0, stream>>>(srcs, tgts, ws);
    chamfer_kernel<<<dim3(1024), dim3(256), 0, stream>>>(ws);
    finish_kernel<<<dim3(1), dim3(256), 0, stream>>>(ws, out);
}